// Round 12
// baseline (292.263 us; speedup 1.0000x reference)
//
#include <hip/hip_runtime.h>

using u16 = unsigned short;
using short8 = __attribute__((ext_vector_type(8))) short;
using f32x4 = __attribute__((ext_vector_type(4))) float;

struct alignas(8) U16x4 { u16 x, y, z, w; };

__device__ __forceinline__ float bf2f(u16 u) {
  return __uint_as_float(((unsigned int)u) << 16);
}
__device__ __forceinline__ u16 f2bf(float f) {
  unsigned int u = __float_as_uint(f);
  unsigned int r = u + 0x7FFFu + ((u >> 16) & 1u);
  return (u16)(r >> 16);
}

// ---------------- K0b: conv weights -> bf16, MFMA-fragment order -------------
__global__ void k_prep_w(const float* __restrict__ wa, const float* __restrict__ wc,
                         u16* __restrict__ Wb) {
  int idx = blockIdx.x * 256 + threadIdx.x;   // 1179648
  int j = idx & 7;
  int l = (idx >> 3) & 63;
  int ks = (idx >> 9) & 3;
  int rest = idx >> 11;
  int tap = rest % 9;
  int rest2 = rest / 9;
  int chunk = rest2 & 3;
  int mt = (rest2 >> 2) & 7;
  int br = rest2 >> 5;
  int co = mt * 16 + (l & 15);
  int ci = chunk * 128 + ks * 32 + (l >> 4) * 8 + j;
  const float* w = br ? wc : wa;
  Wb[idx] = f2bf(w[co * 4608 + ci * 9 + tap]);
}

// ---------------- K0c: 1x1 out-conv weights (128->512) -> bf16 A-frag order --
__global__ void k_prep_w1(const float* __restrict__ wa, const float* __restrict__ wc,
                          u16* __restrict__ W1b) {
  int idx = blockIdx.x * 256 + threadIdx.x;   // 131072
  int j = idx & 7;
  int l = (idx >> 3) & 63;
  int ks = (idx >> 9) & 3;
  int cot = (idx >> 11) & 31;
  int br = idx >> 16;
  int co = cot * 16 + (l & 15);
  int ci = ks * 32 + (l >> 4) * 8 + j;
  const float* w = br ? wc : wa;
  W1b[idx] = f2bf(w[co * 128 + ci]);
}

// ---------------- K0d: qkv weights (160x128) -> bf16 A-frag order ------------
__global__ void k_prep_wqkv(const float* __restrict__ wq, const float* __restrict__ wk,
                            const float* __restrict__ wv, u16* __restrict__ Wq) {
  int idx = blockIdx.x * 256 + threadIdx.x;   // 20480
  if (idx >= 20480) return;
  int j = idx & 7;
  int l = (idx >> 3) & 63;
  int ks = (idx >> 9) & 3;
  int cot = idx >> 11;
  int co = cot * 16 + (l & 15);
  int ci = ks * 32 + (l >> 4) * 8 + j;
  float w = co < 16 ? wq[co * 128 + ci]
          : (co < 32 ? wk[(co - 16) * 128 + ci] : wv[(co - 32) * 128 + ci]);
  Wq[idx] = f2bf(w);
}

// ---------------- K1: BN+ReLU both branches, NHWC bf16; c-split 4 ------------
__global__ __launch_bounds__(256) void k_bnrelu2t(const float* __restrict__ x,
    const float* __restrict__ wa, const float* __restrict__ ba,
    const float* __restrict__ ma, const float* __restrict__ va,
    const float* __restrict__ wc, const float* __restrict__ bc,
    const float* __restrict__ mc, const float* __restrict__ vc,
    u16* __restrict__ xa16, u16* __restrict__ xcb16) {
  __shared__ float sA[128], bA[128], sC[128], bC[128];
  __shared__ u16 ta[64 * 136], tc[64 * 136];
  int t = threadIdx.x;
  int h = blockIdx.x, b = blockIdx.y;
  int c0 = blockIdx.z * 128;
  if (t < 128) {
    int c = c0 + t;
    float s1 = wa[c] * rsqrtf(va[c] + 1e-5f);
    sA[t] = s1; bA[t] = ba[c] - ma[c] * s1;
    float s2 = wc[c] * rsqrtf(vc[c] + 1e-5f);
    sC[t] = s2; bC[t] = bc[c] - mc[c] * s2;
  }
  __syncthreads();
  const float* xb = x + ((size_t)b << 21) + (h << 6);
  u16* oa = xa16 + ((size_t)b << 21) + ((size_t)h << 15);
  u16* oc = xcb16 + ((size_t)b << 21) + ((size_t)h << 15);
  int w = t & 63, cg = t >> 6;
#pragma unroll
  for (int i = 0; i < 8; ++i) {
    int cl = cg * 4 + i * 16;
    int c = c0 + cl;
    const float* xp = xb + (size_t)c * 4096 + w;
    float v0 = xp[0], v1 = xp[4096], v2 = xp[8192], v3 = xp[12288];
    U16x4 pa, pc;
    pa.x = f2bf(fmaxf(fmaf(v0, sA[cl], bA[cl]), 0.f));
    pa.y = f2bf(fmaxf(fmaf(v1, sA[cl + 1], bA[cl + 1]), 0.f));
    pa.z = f2bf(fmaxf(fmaf(v2, sA[cl + 2], bA[cl + 2]), 0.f));
    pa.w = f2bf(fmaxf(fmaf(v3, sA[cl + 3], bA[cl + 3]), 0.f));
    pc.x = f2bf(fmaxf(fmaf(v0, sC[cl], bC[cl]), 0.f));
    pc.y = f2bf(fmaxf(fmaf(v1, sC[cl + 1], bC[cl + 1]), 0.f));
    pc.z = f2bf(fmaxf(fmaf(v2, sC[cl + 2], bC[cl + 2]), 0.f));
    pc.w = f2bf(fmaxf(fmaf(v3, sC[cl + 3], bC[cl + 3]), 0.f));
    *(U16x4*)(ta + w * 136 + cl) = pa;
    *(U16x4*)(tc + w * 136 + cl) = pc;
  }
  __syncthreads();
#pragma unroll
  for (int i = 0; i < 4; ++i) {
    int idx = t + i * 256;
    int ww = idx >> 4, c8 = (idx & 15) << 3;
    *(short8*)(oa + (size_t)ww * 512 + c0 + c8) = *(const short8*)(ta + ww * 136 + c8);
    *(short8*)(oc + (size_t)ww * 512 + c0 + c8) = *(const short8*)(tc + ww * 136 + c8);
  }
}

// ---------------- K2: 3x3 conv, implicit GEMM, NHWC input --------------------
__global__ __launch_bounds__(256, 2) void k_conv3n(
    const u16* __restrict__ xa16, const u16* __restrict__ xcb16,
    const u16* __restrict__ Wb,
    float* __restrict__ sa0, float* __restrict__ sc0,
    u16* __restrict__ sa_nhwc, u16* __restrict__ sc16h, u16* __restrict__ sc16l) {
  __shared__ u16 xs[3 * 66 * 136];
  int t = threadIdx.x;
  int h = blockIdx.x;
  int z = blockIdx.y; int b = z & 1, br = z >> 1;
  int cosplit = blockIdx.z;
  const u16* xb = (br ? xcb16 : xa16) + ((size_t)b << 21);
  const u16* wb = Wb + (size_t)br * 589824;
  float* out = (br ? sc0 : sa0) + (((size_t)b * 128) << 12) + (h << 6);

  int lane = t & 63, wave = t >> 6;
  int mi = lane & 15, quad = lane >> 4;
  int mt = cosplit * 4 + wave;

  if (t < 96) {
    int dh = t >> 5, side = (t >> 4) & 1, c8 = t & 15;
    short8 z8 = {0, 0, 0, 0, 0, 0, 0, 0};
    *(short8*)(xs + (dh * 66 + side * 65) * 136 + c8 * 8) = z8;
  }

  f32x4 acc[4] = {};

  const u16* wlane = wb + lane * 8;
  const u16* bbase0 = xs + mi * 136 + quad * 8;

  for (int chunk = 0; chunk < 4; ++chunk) {
    int ci0 = chunk << 7;
    __syncthreads();
#pragma unroll
    for (int dh = 0; dh < 3; ++dh) {
      int hh = h + dh - 1;
      bool val = (hh >= 0) && (hh < 64);
      const u16* src = xb + (((size_t)hh << 6) << 9) + ci0;
#pragma unroll
      for (int i = 0; i < 4; ++i) {
        int idx = t + i * 256;
        int w = idx >> 4, c8 = (idx & 15) << 3;
        short8 v = {0, 0, 0, 0, 0, 0, 0, 0};
        if (val) v = *(const short8*)(src + ((size_t)w << 9) + c8);
        *(short8*)(xs + (dh * 66 + 1 + w) * 136 + c8) = v;
      }
    }
    __syncthreads();
    const u16* wchunk = wlane + (size_t)(mt * 4 + chunk) * 18432;
    short8 wreg[2][4];
#pragma unroll
    for (int ks = 0; ks < 4; ++ks)
      wreg[0][ks] = *(const short8*)(wchunk + ks * 512);
#pragma unroll
    for (int tap = 0; tap < 9; ++tap) {
      const int cb = tap & 1;
      if (tap < 8) {
        const u16* wn = wchunk + (tap + 1) * 2048;
#pragma unroll
        for (int ks = 0; ks < 4; ++ks)
          wreg[cb ^ 1][ks] = *(const short8*)(wn + ks * 512);
      }
      const int dh = tap / 3, dw = tap % 3;
      const u16* bp = bbase0 + (dh * 66 + dw) * 136;
#pragma unroll
      for (int ks = 0; ks < 4; ++ks) {
        short8 a = wreg[cb][ks];
#pragma unroll
        for (int nt = 0; nt < 4; ++nt) {
          short8 bf = *(const short8*)(bp + nt * 2176 + ks * 32);
          acc[nt] = __builtin_amdgcn_mfma_f32_16x16x32_bf16(a, bf, acc[nt], 0, 0, 0);
        }
      }
    }
  }
#pragma unroll
  for (int nt = 0; nt < 4; ++nt)
#pragma unroll
    for (int r = 0; r < 4; ++r) {
      int co = mt * 16 + quad * 4 + r;
      out[((size_t)co << 12) + nt * 16 + mi] = acc[nt][r];
    }
  if (br == 0) {
    u16* dstq = sa_nhwc + ((size_t)b << 19) + ((size_t)h << 6) * 128;
#pragma unroll
    for (int nt = 0; nt < 4; ++nt) {
      U16x4 v4;
      v4.x = f2bf(acc[nt][0]); v4.y = f2bf(acc[nt][1]);
      v4.z = f2bf(acc[nt][2]); v4.w = f2bf(acc[nt][3]);
      *(U16x4*)(dstq + (size_t)(nt * 16 + mi) * 128 + mt * 16 + quad * 4) = v4;
    }
  } else {
    u16* dh_ = sc16h + ((size_t)b << 19) + (h << 6);
    u16* dl_ = sc16l + ((size_t)b << 19) + (h << 6);
#pragma unroll
    for (int nt = 0; nt < 4; ++nt)
#pragma unroll
      for (int r = 0; r < 4; ++r) {
        int co = mt * 16 + quad * 4 + r;
        float xv = acc[nt][r];
        u16 hi = f2bf(xv);
        float lo = xv - bf2f(hi);
        size_t o = ((size_t)co << 12) + nt * 16 + mi;
        dh_[o] = hi;
        dl_[o] = f2bf(lo);
      }
  }
}

// ---------------- K3: fused q,k,v 1x1 convs via MFMA -------------------------
__global__ __launch_bounds__(256) void k_qkv(
    const u16* __restrict__ sa_nhwc, const u16* __restrict__ Wqkvb,
    const float* __restrict__ bq, const float* __restrict__ bk,
    const float* __restrict__ bv,
    float* __restrict__ qb, u16* __restrict__ k16t, u16* __restrict__ vt16) {
  __shared__ float bs[160];
  int t = threadIdx.x;
  int b = blockIdx.y, n0 = blockIdx.x * 128;
  if (t < 160) bs[t] = t < 16 ? bq[t] : (t < 32 ? bk[t - 16] : bv[t - 32]);
  __syncthreads();
  int lane = t & 63, wave = t >> 6;
  int mi = lane & 15, quad = lane >> 4;
  const u16* xb = sa_nhwc + ((size_t)b << 19) + (size_t)n0 * 128;
  const u16* wb = Wqkvb + lane * 8;
  f32x4 acc[2][10] = {};
  short8 bf[2][4];
#pragma unroll
  for (int ns = 0; ns < 2; ++ns) {
    int n = wave * 32 + ns * 16 + mi;
#pragma unroll
    for (int ks = 0; ks < 4; ++ks)
      bf[ns][ks] = *(const short8*)(xb + (size_t)n * 128 + ks * 32 + quad * 8);
  }
#pragma unroll
  for (int cot = 0; cot < 10; ++cot) {
    short8 a0 = *(const short8*)(wb + (size_t)(cot * 4 + 0) * 512);
    short8 a1 = *(const short8*)(wb + (size_t)(cot * 4 + 1) * 512);
    short8 a2 = *(const short8*)(wb + (size_t)(cot * 4 + 2) * 512);
    short8 a3 = *(const short8*)(wb + (size_t)(cot * 4 + 3) * 512);
#pragma unroll
    for (int ns = 0; ns < 2; ++ns) {
      acc[ns][cot] = __builtin_amdgcn_mfma_f32_16x16x32_bf16(a0, bf[ns][0], acc[ns][cot], 0, 0, 0);
      acc[ns][cot] = __builtin_amdgcn_mfma_f32_16x16x32_bf16(a1, bf[ns][1], acc[ns][cot], 0, 0, 0);
      acc[ns][cot] = __builtin_amdgcn_mfma_f32_16x16x32_bf16(a2, bf[ns][2], acc[ns][cot], 0, 0, 0);
      acc[ns][cot] = __builtin_amdgcn_mfma_f32_16x16x32_bf16(a3, bf[ns][3], acc[ns][cot], 0, 0, 0);
    }
  }
#pragma unroll
  for (int cot = 0; cot < 10; ++cot)
#pragma unroll
    for (int ns = 0; ns < 2; ++ns) {
      int n = n0 + wave * 32 + ns * 16 + mi;
      if (cot == 1) {
        u16 hv[4], lv[4];
#pragma unroll
        for (int r = 0; r < 4; ++r) {
          float v = acc[ns][1][r] + bs[16 + quad * 4 + r];
          u16 hi = f2bf(v);
          hv[r] = hi;
          lv[r] = f2bf(v - bf2f(hi));
        }
        u16* kd = k16t + (((size_t)b << 12) + n) * 32;
        U16x4 h4{hv[0], hv[1], hv[2], hv[3]};
        U16x4 l4{lv[0], lv[1], lv[2], lv[3]};
        *(U16x4*)(kd + quad * 4) = h4;
        *(U16x4*)(kd + 16 + quad * 4) = l4;
      } else {
#pragma unroll
        for (int r = 0; r < 4; ++r) {
          int co = cot * 16 + quad * 4 + r;
          float v = acc[ns][cot][r] + bs[co];
          if (co < 16) qb[((b * 16 + co) << 12) + n] = v;
          else vt16[((size_t)(b * 128 + co - 32) << 12) + n] = f2bf(v);
        }
      }
    }
}

// ---------------- K5: PAM PV, barrier-free wave-local online softmax ---------
// grid (128 nt, 2 b, 2 mqg), 256 thr. Each WAVE is an independent worker:
// (n0..n0+31) x (512 m) x all 128 c. Wave-local running max via shfl_xor;
// P through WAVE-PRIVATE LDS tile (no __syncthreads in loop). 8 m-partials
// (per wave) with (max,sum); combined exactly in k_bout_m.
__global__ __launch_bounds__(256, 2) void k_pam_pv(const float* __restrict__ qb,
    const u16* __restrict__ k16t, const u16* __restrict__ vt16,
    float* __restrict__ pvpart, float* __restrict__ pmax, float* __restrict__ psum) {
  __shared__ u16 pL[4][32 * 36];       // per-wave private [n(32)][m(32)] pad->36
  __shared__ u16 qfh[32 * 16], qfl[32 * 16];
  int t = threadIdx.x;
  int b = blockIdx.y, n0 = blockIdx.x * 32;
  int lane = t & 63, wave = t >> 6;
  int mi = lane & 15, quad = lane >> 4;
  for (int i = t; i < 512; i += 256) {
    int ch = i & 15, nl = i >> 4;
    float qv = qb[((size_t)(b * 16 + ch) << 12) + n0 + nl];
    u16 hi = f2bf(qv);
    qfh[nl * 16 + ch] = hi;
    qfl[nl * 16 + ch] = f2bf(qv - bf2f(hi));
  }
  __syncthreads();   // only barrier: qf ready
  int p = blockIdx.z * 4 + wave;       // partial index 0..7
  int mbeg = p << 9;                   // 512 m per wave
  const u16* kp = k16t + (((size_t)b << 12) + mbeg) * 32;
  const u16* vb = vt16 + ((size_t)b * 128 << 12) + mbeg;
  u16* pw = pL[wave];
  int qoff = (quad & 1) * 8;
  short8 bq1[2], bq2[2];
  bq1[0] = *(const short8*)(qfh + mi * 16 + qoff);
  bq1[1] = *(const short8*)(qfh + (16 + mi) * 16 + qoff);
  bq2[0] = *(const short8*)(qfl + mi * 16 + qoff);
  bq2[1] = *(const short8*)(qfl + (16 + mi) * 16 + qoff);
  f32x4 acc[8][2] = {};
  float mr0 = -1e30f, mr1 = -1e30f, ssum0 = 0.f, ssum1 = 0.f;
  for (int it = 0; it < 16; ++it) {
    int m0 = it << 5;
    // V A-frags for PV (8 c-tiles), issued early
    short8 vreg[8];
#pragma unroll
    for (int ct = 0; ct < 8; ++ct)
      vreg[ct] = *(const short8*)(vb + ((size_t)(ct * 16 + mi) << 12) + m0 + quad * 8);
    // K A-frags (split-bf16 rows)
    const u16* ka = kp + (size_t)m0 * 32;
    short8 a0 = *(const short8*)(ka + mi * 32 + quad * 8);
    short8 a1 = *(const short8*)(ka + (16 + mi) * 32 + quad * 8);
    // energy MFMA (exact split)
    f32x4 e00 = {}, e01 = {}, e10 = {}, e11 = {};
    e00 = __builtin_amdgcn_mfma_f32_16x16x32_bf16(a0, bq1[0], e00, 0, 0, 0);
    e00 = __builtin_amdgcn_mfma_f32_16x16x32_bf16(a0, bq2[0], e00, 0, 0, 0);
    e01 = __builtin_amdgcn_mfma_f32_16x16x32_bf16(a0, bq1[1], e01, 0, 0, 0);
    e01 = __builtin_amdgcn_mfma_f32_16x16x32_bf16(a0, bq2[1], e01, 0, 0, 0);
    e10 = __builtin_amdgcn_mfma_f32_16x16x32_bf16(a1, bq1[0], e10, 0, 0, 0);
    e10 = __builtin_amdgcn_mfma_f32_16x16x32_bf16(a1, bq2[0], e10, 0, 0, 0);
    e11 = __builtin_amdgcn_mfma_f32_16x16x32_bf16(a1, bq1[1], e11, 0, 0, 0);
    e11 = __builtin_amdgcn_mfma_f32_16x16x32_bf16(a1, bq2[1], e11, 0, 0, 0);
    // wave-local per-n max over this 32-m slab
    float lm0 = fmaxf(fmaxf(fmaxf(e00[0], e00[1]), fmaxf(e00[2], e00[3])),
                      fmaxf(fmaxf(e10[0], e10[1]), fmaxf(e10[2], e10[3])));
    float lm1 = fmaxf(fmaxf(fmaxf(e01[0], e01[1]), fmaxf(e01[2], e01[3])),
                      fmaxf(fmaxf(e11[0], e11[1]), fmaxf(e11[2], e11[3])));
    lm0 = fmaxf(lm0, __shfl_xor(lm0, 16)); lm0 = fmaxf(lm0, __shfl_xor(lm0, 32));
    lm1 = fmaxf(lm1, __shfl_xor(lm1, 16)); lm1 = fmaxf(lm1, __shfl_xor(lm1, 32));
    float mn0 = mr0, mn1 = mr1;
    bool need = (__ballot(lm0 > mr0) | __ballot(lm1 > mr1)) != 0ull;
    if (need) {
      mn0 = fmaxf(mr0, lm0); mn1 = fmaxf(mr1, lm1);
      float rs0 = __expf(mr0 - mn0), rs1 = __expf(mr1 - mn1);
#pragma unroll
      for (int ct = 0; ct < 8; ++ct)
#pragma unroll
        for (int r = 0; r < 4; ++r) { acc[ct][0][r] *= rs0; acc[ct][1][r] *= rs1; }
      ssum0 *= rs0; ssum1 *= rs1;
      mr0 = mn0; mr1 = mn1;
    }
    float p00[4], p10[4], p01[4], p11[4];
    float ls0 = 0.f, ls1 = 0.f;
#pragma unroll
    for (int j = 0; j < 4; ++j) {
      p00[j] = __expf(e00[j] - mn0); p10[j] = __expf(e10[j] - mn0);
      p01[j] = __expf(e01[j] - mn1); p11[j] = __expf(e11[j] - mn1);
      ls0 += p00[j] + p10[j];
      ls1 += p01[j] + p11[j];
    }
    ssum0 += ls0;
    ssum1 += ls1;
    // write P to wave-private LDS [n][m]; wave-internal -> no barrier
    U16x4 pk;
    pk.x = f2bf(p00[0]); pk.y = f2bf(p00[1]); pk.z = f2bf(p00[2]); pk.w = f2bf(p00[3]);
    *(U16x4*)(pw + mi * 36 + quad * 4) = pk;
    pk.x = f2bf(p10[0]); pk.y = f2bf(p10[1]); pk.z = f2bf(p10[2]); pk.w = f2bf(p10[3]);
    *(U16x4*)(pw + mi * 36 + 16 + quad * 4) = pk;
    pk.x = f2bf(p01[0]); pk.y = f2bf(p01[1]); pk.z = f2bf(p01[2]); pk.w = f2bf(p01[3]);
    *(U16x4*)(pw + (16 + mi) * 36 + quad * 4) = pk;
    pk.x = f2bf(p11[0]); pk.y = f2bf(p11[1]); pk.z = f2bf(p11[2]); pk.w = f2bf(p11[3]);
    *(U16x4*)(pw + (16 + mi) * 36 + 16 + quad * 4) = pk;
    // B-frags: P[nt*16+n][quad*8..+8]
    short8 b0 = *(const short8*)(pw + mi * 36 + quad * 8);
    short8 b1 = *(const short8*)(pw + (16 + mi) * 36 + quad * 8);
    // PV MFMA over all 128 c
#pragma unroll
    for (int ct = 0; ct < 8; ++ct) {
      acc[ct][0] = __builtin_amdgcn_mfma_f32_16x16x32_bf16(vreg[ct], b0, acc[ct][0], 0, 0, 0);
      acc[ct][1] = __builtin_amdgcn_mfma_f32_16x16x32_bf16(vreg[ct], b1, acc[ct][1], 0, 0, 0);
    }
  }
  // final per-n sum reduce across quads
  ssum0 += __shfl_xor(ssum0, 16); ssum0 += __shfl_xor(ssum0, 32);
  ssum1 += __shfl_xor(ssum1, 16); ssum1 += __shfl_xor(ssum1, 32);
  if (lane < 16) {
    size_t base = ((size_t)(p * 2 + b) << 12) + n0;
    psum[base + mi] = ssum0;
    psum[base + 16 + mi] = ssum1;
    pmax[base + mi] = mr0;
    pmax[base + 16 + mi] = mr1;
  }
  float* dst = pvpart + (((size_t)(p * 2 + b) * 128) << 12);
#pragma unroll
  for (int ct = 0; ct < 8; ++ct)
#pragma unroll
    for (int nt = 0; nt < 2; ++nt)
#pragma unroll
      for (int r = 0; r < 4; ++r) {
        int c = ct * 16 + quad * 4 + r;
        dst[((size_t)c << 12) + n0 + nt * 16 + mi] = acc[ct][nt][r];
      }
}

// ---------------- K6a: CAM Gram energy via MFMA, split-bf16 ------------------
__global__ __launch_bounds__(512) void k_cam_energy_m(
    const u16* __restrict__ sc16h, const u16* __restrict__ sc16l,
    float* __restrict__ epart) {
  int t = threadIdx.x;
  int ti = blockIdx.x, kc = blockIdx.y, b = blockIdx.z;
  int lane = t & 63, wave = t >> 6;
  int mi = lane & 15, quad = lane >> 4;
  const u16* fh = sc16h + ((size_t)b << 19);
  const u16* fl = sc16l + ((size_t)b << 19);
  size_t ao = ((size_t)(ti * 16 + mi) << 12) + (kc << 9) + quad * 8;
  size_t bo = ((size_t)(wave * 16 + mi) << 12) + (kc << 9) + quad * 8;
  const u16* ah = fh + ao; const u16* al = fl + ao;
  const u16* bh = fh + bo; const u16* bl = fl + bo;
  f32x4 acc = {};
#pragma unroll
  for (int k = 0; k < 16; ++k) {
    short8 vah = *(const short8*)(ah + k * 32);
    short8 val = *(const short8*)(al + k * 32);
    short8 vbh = *(const short8*)(bh + k * 32);
    short8 vbl = *(const short8*)(bl + k * 32);
    acc = __builtin_amdgcn_mfma_f32_16x16x32_bf16(vah, vbh, acc, 0, 0, 0);
    acc = __builtin_amdgcn_mfma_f32_16x16x32_bf16(vah, vbl, acc, 0, 0, 0);
    acc = __builtin_amdgcn_mfma_f32_16x16x32_bf16(val, vbh, acc, 0, 0, 0);
  }
  float* ep = epart + (((size_t)(kc * 2 + b)) << 14);
#pragma unroll
  for (int r = 0; r < 4; ++r)
    ep[((ti * 16 + quad * 4 + r) << 7) + wave * 16 + mi] = acc[r];
}

// ---------------- K6b: CAM softmax row (reduce 8 partials) -------------------
__global__ void k_cam_softmax(const float* __restrict__ epart, float* __restrict__ attn) {
  int lane = threadIdx.x;
  int c = blockIdx.x, b = blockIdx.y;
  float e0 = 0.f, e1 = 0.f;
#pragma unroll
  for (int kc = 0; kc < 8; ++kc) {
    const float* ep = epart + (((size_t)(kc * 2 + b)) << 14) + (c << 7);
    e0 += ep[lane];
    e1 += ep[lane + 64];
  }
  float mn = fminf(e0, e1);
#pragma unroll
  for (int off = 32; off >= 1; off >>= 1) mn = fminf(mn, __shfl_xor(mn, off));
  float p0 = __expf(fminf(mn - e0, 0.f)), p1 = __expf(fminf(mn - e1, 0.f));
  float s = p0 + p1;
#pragma unroll
  for (int off = 32; off >= 1; off >>= 1) s += __shfl_xor(s, off);
  float inv = 1.f / s;
  float* a = attn + ((b * 128 + c) << 7);
  a[lane] = p0 * inv;
  a[lane + 64] = p1 * inv;
}

// ---------------- K7: CAM out + residual; c-split 16 -------------------------
__global__ __launch_bounds__(256) void k_cam_out(const float* __restrict__ f,
    const float* __restrict__ attn, const float* __restrict__ gamma,
    float* __restrict__ sc1) {
  __shared__ float at2[128 * 8];
  int t = threadIdx.x;
  int b = blockIdx.z, c0 = blockIdx.y * 8;
  int n = blockIdx.x * 256 + t;
  for (int idx = t; idx < 1024; idx += 256) {
    int d = idx >> 3, cc = idx & 7;
    at2[idx] = attn[((b * 128 + c0 + cc) << 7) + d];
  }
  __syncthreads();
  float acc[8] = {};
  const float* fb = f + ((size_t)b * 128 << 12) + n;
  for (int d = 0; d < 128; ++d) {
    float fv = fb[d << 12];
    const float* ap = at2 + d * 8;
#pragma unroll
    for (int cc = 0; cc < 8; ++cc) acc[cc] = fmaf(ap[cc], fv, acc[cc]);
  }
  float g = gamma[0];
#pragma unroll
  for (int cc = 0; cc < 8; ++cc) {
    size_t o = ((size_t)(b * 128 + c0 + cc) << 12) + n;
    sc1[o] = fmaf(g, acc[cc], f[o]);
  }
}

// ---------------- K8: BN+ReLU + 1x1 conv 128->512 via MFMA -------------------
// sa input = sa0 + sum_q kq*pvq (8-way online-softmax combine, gamma folded).
__global__ __launch_bounds__(256, 2) void k_bout_m(
    const float* __restrict__ sa0, const float* __restrict__ pvpart,
    const float* __restrict__ pmax, const float* __restrict__ psum,
    const float* __restrict__ gamma,
    const float* __restrict__ sc1,
    const float* __restrict__ wa_, const float* __restrict__ ba_,
    const float* __restrict__ ma_, const float* __restrict__ va_,
    const float* __restrict__ wc_, const float* __restrict__ bc_,
    const float* __restrict__ mc_, const float* __restrict__ vc_,
    const u16* __restrict__ W1b, const float* __restrict__ Ba,
    const float* __restrict__ Bc,
    u16* __restrict__ sa2, u16* __restrict__ sc2) {
  __shared__ u16 xl[32 * 136];
  __shared__ float scl[128], shf[128];
  int t = threadIdx.x;
  int n0 = blockIdx.x * 32;
  int b = blockIdx.y, br = blockIdx.z;
  const float* bw = br ? wc_ : wa_;
  const float* bb = br ? bc_ : ba_;
  const float* bm = br ? mc_ : ma_;
  const float* bvv = br ? vc_ : va_;
  if (t < 128) {
    float s = bw[t] * rsqrtf(bvv[t] + 1e-5f);
    scl[t] = s;
    shf[t] = bb[t] - bm[t] * s;
  }
  __syncthreads();
  {
    int nl = t & 31, cio = t >> 5;
    const float* s0 = (br ? sc1 : sa0) + ((size_t)b * 128 << 12) + n0 + nl;
    const float* pq[8];
    float kq[8] = {};
    if (!br) {
      int n = n0 + nl;
      float m[8], s8[8];
#pragma unroll
      for (int q = 0; q < 8; ++q) {
        pq[q] = pvpart + (((size_t)(q * 2 + b) * 128) << 12) + n0 + nl;
        m[q] = pmax[((size_t)(q * 2 + b) << 12) + n];
        s8[q] = psum[((size_t)(q * 2 + b) << 12) + n];
      }
      float M = m[0];
#pragma unroll
      for (int q = 1; q < 8; ++q) M = fmaxf(M, m[q]);
      float den = 0.f;
#pragma unroll
      for (int q = 0; q < 8; ++q) { kq[q] = __expf(m[q] - M); den = fmaf(kq[q], s8[q], den); }
      float inv = gamma[0] / den;
#pragma unroll
      for (int q = 0; q < 8; ++q) kq[q] *= inv;
    }
#pragma unroll
    for (int half = 0; half < 2; ++half) {
      short8 v;
#pragma unroll
      for (int i = 0; i < 8; ++i) {
        int ci = cio * 16 + half * 8 + i;
        float xv = s0[(size_t)ci << 12];
        if (!br) {
          size_t po = (size_t)ci << 12;
          float pv = 0.f;
#pragma unroll
          for (int q = 0; q < 8; ++q) pv = fmaf(kq[q], pq[q][po], pv);
          xv += pv;
        }
        v[i] = (short)f2bf(fmaxf(fmaf(xv, scl[ci], shf[ci]), 0.f));
      }
      *(short8*)(xl + nl * 136 + cio * 16 + half * 8) = v;
    }
  }
  __syncthreads();
  int lane = t & 63, wave = t >> 6;
  int mi = lane & 15, quad = lane >> 4;
  const u16* wb = W1b + (size_t)br * 65536 + lane * 8;
  f32x4 acc[8][2] = {};
#pragma unroll
  for (int ks = 0; ks < 4; ++ks) {
    short8 b0 = *(const short8*)(xl + mi * 136 + ks * 32 + quad * 8);
    short8 b1 = *(const short8*)(xl + (16 + mi) * 136 + ks * 32 + quad * 8);
#pragma unroll
    for (int ct = 0; ct < 8; ++ct) {
      int cot = wave * 8 + ct;
      short8 a = *(const short8*)(wb + ((size_t)(cot * 4 + ks) << 9));
      acc[ct][0] = __builtin_amdgcn_mfma_f32_16x16x32_bf16(a, b0, acc[ct][0], 0, 0, 0);
      acc[ct][1] = __builtin_amdgcn_mfma_f32_16x16x32_bf16(a, b1, acc[ct][1], 0, 0, 0);
    }
  }
  const float* Bs = br ? Bc : Ba;
  u16* dst = br ? sc2 : sa2;
#pragma unroll
  for (int ct = 0; ct < 8; ++ct)
#pragma unroll
    for (int nh = 0; nh < 2; ++nh)
#pragma unroll
      for (int r = 0; r < 4; ++r) {
        int co = (wave * 8 + ct) * 16 + quad * 4 + r;
        dst[((size_t)(b * 512 + co) << 12) + n0 + nh * 16 + mi] =
            f2bf(acc[ct][nh][r] + Bs[co]);
      }
}

// ---------------- K9: fusion + class heads, atomic-free; n-tile 16 -----------
__global__ __launch_bounds__(256) void k_heads2(const u16* __restrict__ sa2,
    const u16* __restrict__ sc2,
    const float* __restrict__ wf, const float* __restrict__ wa, const float* __restrict__ wc,
    const float* __restrict__ bfb, const float* __restrict__ bab,
    const float* __restrict__ bcb,
    float* __restrict__ outFusion, float* __restrict__ outCls) {
  __shared__ float lw[3 * 5 * 512];
  __shared__ float hs[16][15][16];
  int t = threadIdx.x;
  int b = blockIdx.y, n0 = blockIdx.x * 16;
  for (int idx = t; idx < 7680; idx += 256) {
    int arr = idx / 2560, rest = idx - arr * 2560;
    int cls = rest >> 9, co = rest & 511;
    const float* w = arr == 0 ? wf : (arr == 1 ? wa : wc);
    lw[idx] = w[cls * 512 + co];
  }
  __syncthreads();
  int nl = t & 15, ck = t >> 4;
  float acc[15] = {};
  for (int co = ck * 32; co < ck * 32 + 32; ++co) {
    size_t o = ((size_t)(b * 512 + co) << 12) + n0 + nl;
    float a = bf2f(sa2[o]), c = bf2f(sc2[o]);
    float s = a + c;
    outFusion[o] = s;
    const float* lf = lw + co;
#pragma unroll
    for (int cls = 0; cls < 5; ++cls) {
      acc[cls]      = fmaf(lf[cls * 512], s, acc[cls]);
      acc[5 + cls]  = fmaf(lf[2560 + cls * 512], a, acc[5 + cls]);
      acc[10 + cls] = fmaf(lf[5120 + cls * 512], c, acc[10 + cls]);
    }
  }
#pragma unroll
  for (int k = 0; k < 15; ++k) hs[ck][k][nl] = acc[k];
  __syncthreads();
  for (int idx = t; idx < 240; idx += 256) {
    int k = idx >> 4, nl2 = idx & 15;
    float s = 0.f;
#pragma unroll
    for (int c8 = 0; c8 < 16; ++c8) s += hs[c8][k][nl2];
    int arr = k / 5, cls = k - arr * 5;
    float bias = arr == 0 ? bfb[cls] : (arr == 1 ? bab[cls] : bcb[cls]);
    outCls[arr * 40960 + ((b * 5 + cls) << 12) + n0 + nl2] = s + bias;
  }
}

extern "C" void kernel_launch(void* const* d_in, const int* in_sizes, int n_in,
                              void* d_out, int out_size, void* d_ws, size_t ws_size,
                              hipStream_t stream) {
  (void)in_sizes; (void)n_in; (void)out_size; (void)ws_size;
  const float* x      = (const float*)d_in[0];
  const float* bnaw   = (const float*)d_in[1];
  const float* bnab   = (const float*)d_in[2];
  const float* bnam   = (const float*)d_in[3];
  const float* bnav   = (const float*)d_in[4];
  const float* convaw = (const float*)d_in[5];
  const float* bncw   = (const float*)d_in[6];
  const float* bncb   = (const float*)d_in[7];
  const float* bncm   = (const float*)d_in[8];
  const float* bncv   = (const float*)d_in[9];
  const float* convcw = (const float*)d_in[10];
  const float* pqw    = (const float*)d_in[11];
  const float* pqb    = (const float*)d_in[12];
  const float* pkw    = (const float*)d_in[13];
  const float* pkb    = (const float*)d_in[14];
  const float* pvw    = (const float*)d_in[15];
  const float* pvb    = (const float*)d_in[16];
  const float* pgam   = (const float*)d_in[17];
  const float* cgam   = (const float*)d_in[18];
  const float* bna1w  = (const float*)d_in[19];
  const float* bna1b  = (const float*)d_in[20];
  const float* bna1m  = (const float*)d_in[21];
  const float* bna1v  = (const float*)d_in[22];
  const float* conva1w = (const float*)d_in[23];
  const float* conva1b = (const float*)d_in[24];
  const float* bnc1w  = (const float*)d_in[25];
  const float* bnc1b  = (const float*)d_in[26];
  const float* bnc1m  = (const float*)d_in[27];
  const float* bnc1v  = (const float*)d_in[28];
  const float* convc1w = (const float*)d_in[29];
  const float* convc1b = (const float*)d_in[30];
  const float* outaw  = (const float*)d_in[31];
  const float* outab  = (const float*)d_in[32];
  const float* outcw  = (const float*)d_in[33];
  const float* outcb  = (const float*)d_in[34];
  const float* outfw  = (const float*)d_in[35];
  const float* outfb  = (const float*)d_in[36];

  char* wsb = (char*)d_ws;
  size_t off = 0;
  auto take = [&](size_t bytes) -> void* {
    void* p = wsb + off;
    off += (bytes + 255) & ~(size_t)255;
    return p;
  };
  u16*   Wb    = (u16*)take((size_t)2 * 128 * 9 * 512 * 2);
  u16*   W1b   = (u16*)take((size_t)2 * 512 * 128 * 2);
  u16*   Wqkvb = (u16*)take((size_t)160 * 128 * 2);
  u16*   xa16  = (u16*)take((size_t)2 * 512 * 4096 * 2);
  u16*   xcb16 = (u16*)take((size_t)2 * 512 * 4096 * 2);
  float* sa0   = (float*)take((size_t)2 * 128 * 4096 * 4);
  float* sc0   = (float*)take((size_t)2 * 128 * 4096 * 4);
  u16*   sa_nhwc = (u16*)take((size_t)2 * 4096 * 128 * 2);
  u16*   sc16h = (u16*)take((size_t)2 * 128 * 4096 * 2);
  u16*   sc16l = (u16*)take((size_t)2 * 128 * 4096 * 2);
  float* qb    = (float*)take((size_t)2 * 16 * 4096 * 4);
  u16*   k16t  = (u16*)take((size_t)2 * 4096 * 32 * 2);
  u16*   vt16  = (u16*)take((size_t)2 * 128 * 4096 * 2);
  float* pvpart = (float*)take((size_t)8 * 2 * 128 * 4096 * 4);
  float* pmax  = (float*)take((size_t)8 * 2 * 4096 * 4);
  float* psum  = (float*)take((size_t)8 * 2 * 4096 * 4);
  float* sc1   = (float*)take((size_t)2 * 128 * 4096 * 4);
  float* epart = (float*)take((size_t)8 * 2 * 128 * 128 * 4);
  float* attn  = (float*)take((size_t)2 * 128 * 128 * 4);
  u16*   sa2   = (u16*)take((size_t)2 * 512 * 4096 * 2);
  u16*   sc2   = (u16*)take((size_t)2 * 512 * 4096 * 2);

  float* outF = (float*)d_out;
  float* outCls = outF + (size_t)2 * 512 * 4096;

  k_prep_w<<<4608, 256, 0, stream>>>(convaw, convcw, Wb);
  k_prep_w1<<<512, 256, 0, stream>>>(conva1w, convc1w, W1b);
  k_prep_wqkv<<<80, 256, 0, stream>>>(pqw, pkw, pvw, Wqkvb);
  k_bnrelu2t<<<dim3(64, 2, 4), 256, 0, stream>>>(x, bnaw, bnab, bnam, bnav,
                                                 bncw, bncb, bncm, bncv, xa16, xcb16);
  k_conv3n<<<dim3(64, 4, 2), 256, 0, stream>>>(xa16, xcb16, Wb, sa0, sc0,
                                               sa_nhwc, sc16h, sc16l);
  k_qkv<<<dim3(32, 2), 256, 0, stream>>>(sa_nhwc, Wqkvb, pqb, pkb, pvb,
                                         qb, k16t, vt16);
  k_pam_pv<<<dim3(128, 2, 2), 256, 0, stream>>>(qb, k16t, vt16, pvpart, pmax, psum);
  k_cam_energy_m<<<dim3(8, 8, 2), 512, 0, stream>>>(sc16h, sc16l, epart);
  k_cam_softmax<<<dim3(128, 2), 64, 0, stream>>>(epart, attn);
  k_cam_out<<<dim3(16, 16, 2), 256, 0, stream>>>(sc0, attn, cgam, sc1);
  k_bout_m<<<dim3(128, 2, 2), 256, 0, stream>>>(sa0, pvpart, pmax, psum, pgam, sc1,
      bna1w, bna1b, bna1m, bna1v, bnc1w, bnc1b, bnc1m, bnc1v,
      W1b, conva1b, convc1b, sa2, sc2);
  k_heads2<<<dim3(256, 2), 256, 0, stream>>>(sa2, sc2, outfw, outaw, outcw,
                                             outfb, outab, outcb, outF, outCls);
}